// Round 7
// baseline (100.994 us; speedup 1.0000x reference)
//
#include <hip/hip_runtime.h>

// out[b,c,h,w] = (c % 2 == 0) ? relu(x) : x ; x: (16,64,256,256) f32 contiguous.
// Memory-bound streaming op. float4, unroll-4, block-contiguous 16 KiB tiles.
// Round 6 (nt loads + cached stores) = 82.0 us = 6.55 TB/s (best).
// This round: ablate nt on loads too (plain cached loads + cached stores).
//
// Channel period = 16384 float4s; 1024 | 16384 => block entirely within one
// channel; mask = ((b >> 4) & 1) == 0 (block-uniform, zero divergence).

typedef float f32x4 __attribute__((ext_vector_type(4)));

__device__ __forceinline__ f32x4 relu4(f32x4 v) {
    v.x = fmaxf(v.x, 0.0f);
    v.y = fmaxf(v.y, 0.0f);
    v.z = fmaxf(v.z, 0.0f);
    v.w = fmaxf(v.w, 0.0f);
    return v;
}

__global__ __launch_bounds__(256) void Grid2DPartialPositiver_kernel(
    const f32x4* __restrict__ in, f32x4* __restrict__ out, unsigned int n4) {
    const unsigned int b = blockIdx.x;
    const unsigned int base = b * 1024u + threadIdx.x;
    const bool pos = ((b >> 4) & 1u) == 0u;  // even channel -> relu

    const unsigned int i0 = base;
    const unsigned int i1 = base + 256u;
    const unsigned int i2 = base + 512u;
    const unsigned int i3 = base + 768u;

    if (i3 < n4) {
        f32x4 v0 = in[i0];
        f32x4 v1 = in[i1];
        f32x4 v2 = in[i2];
        f32x4 v3 = in[i3];
        if (pos) {
            v0 = relu4(v0);
            v1 = relu4(v1);
            v2 = relu4(v2);
            v3 = relu4(v3);
        }
        out[i0] = v0;
        out[i1] = v1;
        out[i2] = v2;
        out[i3] = v3;
    } else {
        for (unsigned int i = i0; i < n4; i += 256u) {
            f32x4 v = in[i];
            if (((i >> 14) & 1u) == 0u) v = relu4(v);
            out[i] = v;
        }
    }
}

extern "C" void kernel_launch(void* const* d_in, const int* in_sizes, int n_in,
                              void* d_out, int out_size, void* d_ws, size_t ws_size,
                              hipStream_t stream) {
    const f32x4* x = (const f32x4*)d_in[0];
    f32x4* out = (f32x4*)d_out;
    const unsigned int n4 = (unsigned int)(out_size / 4);  // 16,777,216
    const int block = 256;
    // one contiguous 1024-float4 (16 KiB) tile per block: 16384 blocks
    const int grid = (int)((n4 + 1023u) / 1024u);
    Grid2DPartialPositiver_kernel<<<grid, block, 0, stream>>>(x, out, n4);
}

// Round 8
// 82.291 us; speedup vs baseline: 1.2273x; 1.2273x over previous
//
#include <hip/hip_runtime.h>

// out[b,c,h,w] = (c % 2 == 0) ? relu(x) : x ; x: (16,64,256,256) f32 contiguous.
// Memory-bound streaming op. FINAL (round-6 config, best of ablation matrix):
//   - float4 (16B/lane), unroll-4, block-contiguous 16 KiB tiles
//   - nontemporal LOADS (bypass L2 for read-once data, keep L2 for writes)
//   - cached STORES (L2 write-back buffering; nt write-through cost 12%)
//   - block-uniform relu mask => zero divergence
// 82.0 us = 6.55 TB/s mixed R+W (above 6.29 TB/s nt-copy ceiling, ~94% of
// the 7.0 TB/s write-only fill rate). Ablations: nt/nt=93.2us,
// cached/cached=101.0us, unroll-8 variants regressed, grid-stride regressed.
//
// Channel period = 16384 float4s; 1024 | 16384 => block entirely within one
// channel; mask = ((b >> 4) & 1) == 0 (even channel -> relu).

typedef float f32x4 __attribute__((ext_vector_type(4)));

__device__ __forceinline__ f32x4 relu4(f32x4 v) {
    v.x = fmaxf(v.x, 0.0f);
    v.y = fmaxf(v.y, 0.0f);
    v.z = fmaxf(v.z, 0.0f);
    v.w = fmaxf(v.w, 0.0f);
    return v;
}

__global__ __launch_bounds__(256) void Grid2DPartialPositiver_kernel(
    const f32x4* __restrict__ in, f32x4* __restrict__ out, unsigned int n4) {
    const unsigned int b = blockIdx.x;
    const unsigned int base = b * 1024u + threadIdx.x;
    const bool pos = ((b >> 4) & 1u) == 0u;  // even channel -> relu

    const unsigned int i0 = base;
    const unsigned int i1 = base + 256u;
    const unsigned int i2 = base + 512u;
    const unsigned int i3 = base + 768u;

    if (i3 < n4) {
        f32x4 v0 = __builtin_nontemporal_load(&in[i0]);
        f32x4 v1 = __builtin_nontemporal_load(&in[i1]);
        f32x4 v2 = __builtin_nontemporal_load(&in[i2]);
        f32x4 v3 = __builtin_nontemporal_load(&in[i3]);
        if (pos) {
            v0 = relu4(v0);
            v1 = relu4(v1);
            v2 = relu4(v2);
            v3 = relu4(v3);
        }
        out[i0] = v0;
        out[i1] = v1;
        out[i2] = v2;
        out[i3] = v3;
    } else {
        for (unsigned int i = i0; i < n4; i += 256u) {
            f32x4 v = __builtin_nontemporal_load(&in[i]);
            if (((i >> 14) & 1u) == 0u) v = relu4(v);
            out[i] = v;
        }
    }
}

extern "C" void kernel_launch(void* const* d_in, const int* in_sizes, int n_in,
                              void* d_out, int out_size, void* d_ws, size_t ws_size,
                              hipStream_t stream) {
    const f32x4* x = (const f32x4*)d_in[0];
    f32x4* out = (f32x4*)d_out;
    const unsigned int n4 = (unsigned int)(out_size / 4);  // 16,777,216
    const int block = 256;
    // one contiguous 1024-float4 (16 KiB) tile per block: 16384 blocks
    const int grid = (int)((n4 + 1023u) / 1024u);
    Grid2DPartialPositiver_kernel<<<grid, block, 0, stream>>>(x, out, n4);
}